// Round 6
// baseline (520.668 us; speedup 1.0000x reference)
//
#include <hip/hip_runtime.h>
#include <hip/hip_bf16.h>
#include <math.h>

#define Bn 4
#define Nn 2048
#define FIN 128
#define Hh 4
#define HIDn 32
#define En 4
#define ZS 64            // i-splits in K2
#define RPT (Nn / ZS)    // 32 rows per block

typedef __bf16 bf16x8 __attribute__((ext_vector_type(8)));
typedef __bf16 bf16x4 __attribute__((ext_vector_type(4)));
typedef float  f32x4  __attribute__((ext_vector_type(4)));
typedef float  f32x4v __attribute__((ext_vector_type(4)));
typedef int    i32x4v __attribute__((ext_vector_type(4)));

// K1: ht = h @ W  (B,N,128); emit htT bf16 [b][h][hid][n], s_i/s_j fp32 [b][h][n]
//     Also zeroes the D accumulator (128 KB) so K2 can atomically reduce into it.
__global__ __launch_bounds__(256) void k1_proj(const float* __restrict__ h,
    const float* __restrict__ W, const float* __restrict__ a,
    __bf16* __restrict__ htT, float* __restrict__ s_i, float* __restrict__ s_j,
    float* __restrict__ D)
{
    __shared__ float hl[16][FIN];
    const int b  = blockIdx.y;
    const int n0 = blockIdx.x * 16;
    const int t  = threadIdx.x;
    // zero D: 512 blocks x 64 floats = 32768 = Bn*Hh*Nn
    const int bid = blockIdx.y * gridDim.x + blockIdx.x;
    if (t < 64) D[bid * 64 + t] = 0.f;
    for (int k = t; k < 16 * FIN; k += 256) {
        int r = k >> 7, f = k & 127;
        hl[r][f] = h[((size_t)(b * Nn + n0 + r)) * FIN + f];
    }
    __syncthreads();
    const int d   = t & 127;
    const int ng  = t >> 7;
    const int hh  = d >> 5;
    const int hid = d & 31;
    float acc[8];
#pragma unroll
    for (int r = 0; r < 8; r++) acc[r] = 0.f;
    for (int f = 0; f < FIN; f++) {
        float wv = W[f * 128 + d];
#pragma unroll
        for (int r = 0; r < 8; r++) acc[r] = fmaf(hl[ng * 8 + r][f], wv, acc[r]);
    }
    const float ai = a[hh * 68 + hid];
    const float aj = a[hh * 68 + 32 + hid];
#pragma unroll
    for (int r = 0; r < 8; r++) {
        float vi = acc[r] * ai;
        float vj = acc[r] * aj;
#pragma unroll
        for (int m = 16; m >= 1; m >>= 1) {
            vi += __shfl_xor(vi, m, 64);
            vj += __shfl_xor(vj, m, 64);
        }
        if (hid == 0) {
            int n = n0 + ng * 8 + r;
            s_i[(b * Hh + hh) * Nn + n] = vi;
            s_j[(b * Hh + hh) * Nn + n] = vj;
        }
    }
    bf16x8 pack;
#pragma unroll
    for (int r = 0; r < 8; r++) pack[r] = (__bf16)acc[r];
    *(bf16x8*)(htT + ((size_t)((b * Hh + hh) * HIDn + hid)) * Nn + n0 + ng * 8) = pack;
}

// K2: P[b][h][i][j] = adj ? exp(s_i + s_j + edge.a_e) : 0  (bf16, unnormalized)
//     4 j's/thread; per-(hh,j) D accumulated in registers over the block's i-range,
//     then one hardware fp atomicAdd each (64 contenders/address) -> Dpart+K3a deleted.
//     edge/adj nontemporal so P survives in L3 for K4.
__global__ __launch_bounds__(256) void k2_pexp(const float* __restrict__ edge,
    const int* __restrict__ adj, const float* __restrict__ a,
    const float* __restrict__ s_i, const float* __restrict__ s_j,
    __bf16* __restrict__ P, float* __restrict__ D)
{
    __shared__ float si_l[4][RPT];
    const int b  = blockIdx.y;
    const int z  = blockIdx.z;
    const int i0 = z * RPT;
    const int t  = threadIdx.x;
    const int j0 = blockIdx.x * 1024 + t * 4;
    if (t < 4 * RPT)
        si_l[t >> 5][t & 31] = s_i[(b * Hh + (t >> 5)) * Nn + i0 + (t & 31)];
    float ae[4][4];
#pragma unroll
    for (int hh = 0; hh < 4; hh++)
#pragma unroll
        for (int e = 0; e < 4; e++) ae[hh][e] = a[hh * 68 + 64 + e];
    f32x4v sj[4];
#pragma unroll
    for (int hh = 0; hh < 4; hh++)
        sj[hh] = *(const f32x4v*)(s_j + (b * Hh + hh) * Nn + j0);
    __syncthreads();
    f32x4v Dacc[4];
#pragma unroll
    for (int hh = 0; hh < 4; hh++) Dacc[hh] = (f32x4v){0.f, 0.f, 0.f, 0.f};
    const float* ep = edge + ((size_t)(b * Nn + i0)) * Nn * En + (size_t)j0 * En;
    const int*   ap = adj  + ((size_t)(b * Nn + i0)) * Nn + j0;
    __bf16*      pp = P    + ((size_t)(b * Hh) * Nn + i0) * Nn + j0;
    const size_t PS = (size_t)Nn * Nn;   // head-plane stride
#pragma unroll 2
    for (int ii = 0; ii < RPT; ii++) {
        f32x4v e[4];
#pragma unroll
        for (int k = 0; k < 4; k++)
            e[k] = __builtin_nontemporal_load(((const f32x4v*)ep) + k);
        const i32x4v av = __builtin_nontemporal_load((const i32x4v*)ap);
        ep += (size_t)Nn * En;
        ap += Nn;
#pragma unroll
        for (int hh = 0; hh < 4; hh++) {
            const float base = si_l[hh][ii];
            bf16x4 pv;
#pragma unroll
            for (int jj = 0; jj < 4; jj++) {
                float dd = base + sj[hh][jj];
                dd = fmaf(e[jj][0], ae[hh][0], dd);
                dd = fmaf(e[jj][1], ae[hh][1], dd);
                dd = fmaf(e[jj][2], ae[hh][2], dd);
                dd = fmaf(e[jj][3], ae[hh][3], dd);
                const float p = (av[jj] > 0) ? __expf(dd) : 0.f;
                Dacc[hh][jj] += p;
                pv[jj] = (__bf16)p;
            }
            *(bf16x4*)(pp + hh * PS) = pv;
        }
        pp += Nn;
    }
#pragma unroll
    for (int hh = 0; hh < 4; hh++)
#pragma unroll
        for (int jj = 0; jj < 4; jj++)
            unsafeAtomicAdd(&D[(b * Hh + hh) * Nn + j0 + jj], Dacc[hh][jj]);
}

// K3: htD[bh][d][j] = htT[bh][d][j] / D[bh][j]  (bf16x8 vectorized, 512 blocks)
__global__ __launch_bounds__(256) void k3_scale(const float* __restrict__ D,
    const __bf16* __restrict__ htT, __bf16* __restrict__ htD)
{
    const int idx = blockIdx.x * 256 + threadIdx.x;   // [bh][d][n/8]
    const int oct = idx & 255;
    const int d   = (idx >> 8) & 31;
    const int bh  = idx >> 13;
    const int n0  = oct * 8;
    const size_t o = ((size_t)(bh * HIDn + d)) * Nn + n0;
    const bf16x8 v = *(const bf16x8*)(htT + o);
    const float4 s0 = *(const float4*)(D + bh * Nn + n0);
    const float4 s1 = *(const float4*)(D + bh * Nn + n0 + 4);
    float r[8];
    r[0] = (s0.x > 0.f) ? 1.f / s0.x : 0.f;
    r[1] = (s0.y > 0.f) ? 1.f / s0.y : 0.f;
    r[2] = (s0.z > 0.f) ? 1.f / s0.z : 0.f;
    r[3] = (s0.w > 0.f) ? 1.f / s0.w : 0.f;
    r[4] = (s1.x > 0.f) ? 1.f / s1.x : 0.f;
    r[5] = (s1.y > 0.f) ? 1.f / s1.y : 0.f;
    r[6] = (s1.z > 0.f) ? 1.f / s1.z : 0.f;
    r[7] = (s1.w > 0.f) ? 1.f / s1.w : 0.f;
    bf16x8 w;
#pragma unroll
    for (int k = 0; k < 8; k++) w[k] = (__bf16)((float)v[k] * r[k]);
    *(bf16x8*)(htD + o) = w;
}

// K4: out[b][i][h*32+d] = sum_j P[bh][i][j] * htD[bh][d][j]   (pure bf16 GEMM, no LDS)
__global__ __launch_bounds__(256) void k4_gemm(const __bf16* __restrict__ P,
    const __bf16* __restrict__ htD, float* __restrict__ out)
{
    const int bh   = blockIdx.y;
    const int t    = threadIdx.x;
    const int w    = t >> 6;
    const int lane = t & 63;
    const int quad = lane >> 4;
    const int lrow = lane & 15;
    const int i0   = blockIdx.x * 64 + w * 16;

    const __bf16* Arow = P   + (size_t)bh * Nn * Nn + (size_t)(i0 + lrow) * Nn + quad * 8;
    const __bf16* B0   = htD + (size_t)bh * HIDn * Nn + (size_t)lrow * Nn + quad * 8;
    const __bf16* B1   = B0 + (size_t)16 * Nn;

    f32x4 acc0 = {0.f, 0.f, 0.f, 0.f};
    f32x4 acc1 = {0.f, 0.f, 0.f, 0.f};
#pragma unroll 4
    for (int k0 = 0; k0 < Nn; k0 += 32) {
        bf16x8 af = *(const bf16x8*)(Arow + k0);
        bf16x8 b0 = *(const bf16x8*)(B0 + k0);
        bf16x8 b1 = *(const bf16x8*)(B1 + k0);
        acc0 = __builtin_amdgcn_mfma_f32_16x16x32_bf16(af, b0, acc0, 0, 0, 0);
        acc1 = __builtin_amdgcn_mfma_f32_16x16x32_bf16(af, b1, acc1, 0, 0, 0);
    }
    const int b = bh >> 2, hh = bh & 3;
#pragma unroll
    for (int r = 0; r < 4; r++) {
        const int i = i0 + quad * 4 + r;
        out[((size_t)(b * Nn + i)) * 128 + hh * 32 + 0  + lrow] = acc0[r];
        out[((size_t)(b * Nn + i)) * 128 + hh * 32 + 16 + lrow] = acc1[r];
    }
}

extern "C" void kernel_launch(void* const* d_in, const int* in_sizes, int n_in,
                              void* d_out, int out_size, void* d_ws, size_t ws_size,
                              hipStream_t stream)
{
    const float* h    = (const float*)d_in[0];
    const int*   adj  = (const int*)d_in[1];
    const float* edge = (const float*)d_in[2];
    const float* W    = (const float*)d_in[3];
    const float* a    = (const float*)d_in[4];
    float* out = (float*)d_out;

    char* ws = (char*)d_ws;
    __bf16* htT = (__bf16*)(ws);                   //  2,097,152 B
    __bf16* htD = (__bf16*)(ws + 2097152);         //  2,097,152 B
    float*  s_i = (float*)(ws + 4194304);          //    131,072 B
    float*  s_j = (float*)(ws + 4325376);          //    131,072 B
    float*  D   = (float*)(ws + 4456448);          //    131,072 B
    __bf16* P   = (__bf16*)(ws + 4587520);         // 134,217,728 B  (total ~139 MB)

    k1_proj <<<dim3(Nn / 16, Bn),       256, 0, stream>>>(h, W, a, htT, s_i, s_j, D);
    k2_pexp <<<dim3(Nn / 1024, Bn, ZS), 256, 0, stream>>>(edge, adj, a, s_i, s_j, P, D);
    k3_scale<<<dim3(Bn * Hh * HIDn * Nn / 8 / 256), 256, 0, stream>>>(D, htT, htD);
    k4_gemm <<<dim3(Nn / 64, Bn * Hh),  256, 0, stream>>>(P, htD, out);
}